// Round 1
// baseline (278.783 us; speedup 1.0000x reference)
//
#include <hip/hip_runtime.h>
#include <hip/hip_bf16.h>

// Scalar loss = mean((output-target)^2) + ALPHA * sum(masked cosine Gram of
// V[128][196608]), V[f][d] = conv_w[o][i][f][k], d=(o,i,k).
//
// Gram G = V V^T done in bf16 MFMA (16x16x32). Identical fragment data serves
// both A (row-tile) and B (col-tile) operands since G is a Gram matrix.

typedef __attribute__((ext_vector_type(8))) short bf16x8;   // 8 bf16 = 4 VGPR
typedef __attribute__((ext_vector_type(4))) float f32x4;

#define ALPHA 0.0005f
#define TAU 0.2f

#define FDIM 128            // filters (Gram size)
#define NSITES 65536        // 256*256
#define KW 3
#define SPS 32              // sites staged per chunk
#define CHUNK_FLOATS (SPS * FDIM * KW)      // 12288 floats = 48 KB
#define LDS_STRIDE 104      // 96 + 8 pad bf16 -> 208 B row stride (16B mult)
#define GRAM_NBLK 512
#define CHUNKS_PER_BLK 4    // 512 * 4 * 32 = 65536 sites
#define GRAM_ELEMS (FDIM * FDIM)            // 16384

__device__ inline unsigned short f2bf(float x) {
    __hip_bfloat16 h = __float2bfloat16(x);
    return *reinterpret_cast<unsigned short*>(&h);
}

// ---------------------------------------------------------------- MSE kernel
__global__ void __launch_bounds__(256) mse_kernel(
        const float* __restrict__ o, const float* __restrict__ t,
        float* __restrict__ mse_slot) {
    const int n4 = (8192 * 1000) / 4;       // 2,048,000 float4
    float s = 0.f;
    for (int i = blockIdx.x * blockDim.x + threadIdx.x; i < n4;
         i += gridDim.x * blockDim.x) {
        float4 a = reinterpret_cast<const float4*>(o)[i];
        float4 b = reinterpret_cast<const float4*>(t)[i];
        float dx = a.x - b.x, dy = a.y - b.y, dz = a.z - b.z, dw = a.w - b.w;
        s += dx * dx + dy * dy + dz * dz + dw * dw;
    }
    for (int off = 32; off; off >>= 1) s += __shfl_down(s, off);
    __shared__ float ws_[4];
    if ((threadIdx.x & 63) == 0) ws_[threadIdx.x >> 6] = s;
    __syncthreads();
    if (threadIdx.x == 0)
        atomicAdd(mse_slot, ws_[0] + ws_[1] + ws_[2] + ws_[3]);
}

// --------------------------------------------------------------- Gram kernel
// Block: 256 threads (4 waves). Wave w owns output rows [32w, 32w+32).
// Per chunk: stage 32 sites -> bf16 LDS [128][96] (kk = k*32 + s), then
// 3 MFMA K-steps of 32. acc[2][8] f32x4 per lane (full 128x128 per block).
template <int USE_ATOMIC>
__global__ void __launch_bounds__(256, 2) gram_kernel(
        const float* __restrict__ conv, float* __restrict__ out) {
    __shared__ unsigned short lds[FDIM * LDS_STRIDE];
    const int tid = threadIdx.x;
    const int lane = tid & 63;
    const int wave = tid >> 6;

    f32x4 acc[2][8];
#pragma unroll
    for (int r = 0; r < 2; ++r)
#pragma unroll
        for (int c = 0; c < 8; ++c) acc[r][c] = (f32x4)0.f;

    for (int c = 0; c < CHUNKS_PER_BLK; ++c) {
        const int chunk = blockIdx.x * CHUNKS_PER_BLK + c;
        const float4* src4 = reinterpret_cast<const float4*>(
            conv + (size_t)chunk * CHUNK_FLOATS);
        // ---- stage: 3072 float4 loads, transposed bf16 writes
#pragma unroll
        for (int it = 0; it < CHUNK_FLOATS / 4 / 256; ++it) {   // 12 iters
            int fi4 = tid + it * 256;
            float4 v = src4[fi4];
            int base = fi4 * 4;
#pragma unroll
            for (int u = 0; u < 4; ++u) {
                int idx = base + u;
                int s = idx / (FDIM * KW);          // site in [0,32)
                int r = idx - s * (FDIM * KW);
                int f = r / KW;
                int k = r - f * KW;
                float x = (u == 0) ? v.x : (u == 1) ? v.y : (u == 2) ? v.z : v.w;
                lds[f * LDS_STRIDE + k * SPS + s] = f2bf(x);
            }
        }
        __syncthreads();
        // ---- compute: 3 K-steps x (8 frag loads + 16 MFMA per wave)
#pragma unroll
        for (int ks = 0; ks < 3; ++ks) {
            bf16x8 frag[8];
            const int koff = ks * 32 + (lane >> 4) * 8;
#pragma unroll
            for (int t = 0; t < 8; ++t)
                frag[t] = *reinterpret_cast<const bf16x8*>(
                    &lds[(t * 16 + (lane & 15)) * LDS_STRIDE + koff]);
#pragma unroll
            for (int r = 0; r < 2; ++r)
#pragma unroll
                for (int cc = 0; cc < 8; ++cc)
                    acc[r][cc] = __builtin_amdgcn_mfma_f32_16x16x32_bf16(
                        frag[wave * 2 + r], frag[cc], acc[r][cc], 0, 0, 0);
        }
        __syncthreads();
    }

    // ---- write out. C/D layout: col = lane&15, row = (lane>>4)*4 + j
    float* my = USE_ATOMIC ? out : out + (size_t)blockIdx.x * GRAM_ELEMS;
#pragma unroll
    for (int r = 0; r < 2; ++r) {
        const int row0 = wave * 32 + r * 16 + ((lane >> 4) << 2);
        const int colb = lane & 15;
#pragma unroll
        for (int cc = 0; cc < 8; ++cc) {
            const int col = cc * 16 + colb;
#pragma unroll
            for (int j = 0; j < 4; ++j) {
                if (USE_ATOMIC)
                    atomicAdd(&my[(row0 + j) * FDIM + col], acc[r][cc][j]);
                else
                    my[(row0 + j) * FDIM + col] = acc[r][cc][j];
            }
        }
    }
}

// ------------------------------------------------- partial-Gram tree reduce
// 512 blocks x 256: thread handles entry e = gid & 16383, slice gid>>14 (8
// slices of 64 partials each), atomicAdd into gram (zero-init'd by memset).
__global__ void __launch_bounds__(256) gram_reduce(
        const float* __restrict__ partials, float* __restrict__ gram) {
    const int gid = blockIdx.x * 256 + threadIdx.x;
    const int e = gid & (GRAM_ELEMS - 1);
    const int slice = gid >> 14;            // 0..7
    float s = 0.f;
#pragma unroll 8
    for (int b = slice * 64; b < slice * 64 + 64; ++b)
        s += partials[(size_t)b * GRAM_ELEMS + e];
    atomicAdd(&gram[e], s);
}

// ------------------------------------------------------------ finalize
__global__ void __launch_bounds__(256) finalize_kernel(
        const float* __restrict__ gram, const float* __restrict__ mse_slot,
        float* __restrict__ out) {
    __shared__ float rn[FDIM];
    __shared__ float red[4];
    const int tid = threadIdx.x;
    if (tid < FDIM) rn[tid] = rsqrtf(gram[tid * (FDIM + 1)]);
    __syncthreads();
    float s = 0.f;
    for (int i = tid; i < GRAM_ELEMS; i += 256) {
        const int row = i >> 7, col = i & 127;
        const float g = gram[i] * rn[row] * rn[col];
        if (row != col && g > TAU && g <= 1.0f) s += g;
    }
    for (int off = 32; off; off >>= 1) s += __shfl_down(s, off);
    if ((tid & 63) == 0) red[tid >> 6] = s;
    __syncthreads();
    if (tid == 0)
        out[0] = mse_slot[0] * (1.0f / 8192000.0f) +
                 ALPHA * (red[0] + red[1] + red[2] + red[3]);
}

extern "C" void kernel_launch(void* const* d_in, const int* in_sizes, int n_in,
                              void* d_out, int out_size, void* d_ws, size_t ws_size,
                              hipStream_t stream) {
    const float* output = (const float*)d_in[0];
    const float* target = (const float*)d_in[1];
    const float* conv   = (const float*)d_in[2];
    float* out = (float*)d_out;

    float* wsf      = (float*)d_ws;
    float* mse_slot = wsf;                       // 1 float (+pad to 64)
    float* gram     = wsf + 64;                  // 16384 floats
    float* partials = wsf + 64 + GRAM_ELEMS;     // 512 * 16384 floats

    const size_t need_partials =
        (64 + GRAM_ELEMS + (size_t)GRAM_NBLK * GRAM_ELEMS) * sizeof(float);

    // zero mse slot + gram accumulator (atomic targets)
    hipMemsetAsync(d_ws, 0, (64 + GRAM_ELEMS) * sizeof(float), stream);

    mse_kernel<<<2048, 256, 0, stream>>>(output, target, mse_slot);

    if (ws_size >= need_partials) {
        gram_kernel<0><<<GRAM_NBLK, 256, 0, stream>>>(conv, partials);
        gram_reduce<<<512, 256, 0, stream>>>(partials, gram);
    } else {
        gram_kernel<1><<<GRAM_NBLK, 256, 0, stream>>>(conv, gram);
    }

    finalize_kernel<<<1, 256, 0, stream>>>(gram, mse_slot, out);
}

// Round 2
// 93.281 us; speedup vs baseline: 2.9886x; 2.9886x over previous
//
#include <hip/hip_runtime.h>
#include <hip/hip_bf16.h>

// loss = mean((output-target)^2) + ALPHA * sum(masked cosine Gram of
// V[128][196608]), V[f][d] = conv_w[o][i][f][k], d=(site,k), site=(o,i).
//
// Gram G = V V^T via bf16 MFMA 16x16x32. A- and B-fragments of a Gram share
// the same lane->element map, so one LDS tile serves both operands.
// CRITICAL: all register-array indices are compile-time (rule #20) — the
// round-1 kernel indexed frag[wave*2+r] with runtime wave -> scratch spill.

typedef __attribute__((ext_vector_type(8))) short bf16x8;   // 8 bf16 = 4 VGPR
typedef __attribute__((ext_vector_type(4))) float f32x4;

#define ALPHA 0.0005f
#define TAU 0.2f

#define FDIM 128            // filters (Gram size)
#define KW 3
#define SPS 32              // sites staged per chunk
#define NPAIR 16            // site pairs per chunk
#define F4_PER_SITE 96      // 384 floats per site
#define CHUNK_FLOATS (SPS * FDIM * KW)      // 12288 floats = 48 KB
#define DSTRIDE_DW 52       // LDS row stride in dwords (48 data + 4 pad)
#define GRAM_NBLK 512
#define CHUNKS_PER_BLK 4    // 512 * 4 * 32 = 65536 sites
#define GRAM_ELEMS (FDIM * FDIM)            // 16384

// branchless RNE f32->bf16 pair pack (inputs are finite random normals)
__device__ inline unsigned int pack_bf2(float lo, float hi) {
    union { float f; unsigned int u; } a, b;
    a.f = lo; b.f = hi;
    unsigned int al = (a.u + 0x7fffu + ((a.u >> 16) & 1u)) >> 16;
    unsigned int bh = (b.u + 0x7fffu + ((b.u >> 16) & 1u)) & 0xffff0000u;
    return (al & 0xffffu) | bh;
}

// ---------------------------------------------------------------- MSE kernel
__global__ void __launch_bounds__(256) mse_kernel(
        const float* __restrict__ o, const float* __restrict__ t,
        float* __restrict__ mse_slot) {
    const int n4 = (8192 * 1000) / 4;       // 2,048,000 float4
    float s = 0.f;
    for (int i = blockIdx.x * blockDim.x + threadIdx.x; i < n4;
         i += gridDim.x * blockDim.x) {
        float4 a = reinterpret_cast<const float4*>(o)[i];
        float4 b = reinterpret_cast<const float4*>(t)[i];
        float dx = a.x - b.x, dy = a.y - b.y, dz = a.z - b.z, dw = a.w - b.w;
        s += dx * dx + dy * dy + dz * dz + dw * dw;
    }
    for (int off = 32; off; off >>= 1) s += __shfl_down(s, off);
    __shared__ float ws_[4];
    if ((threadIdx.x & 63) == 0) ws_[threadIdx.x >> 6] = s;
    __syncthreads();
    if (threadIdx.x == 0)
        atomicAdd(mse_slot, ws_[0] + ws_[1] + ws_[2] + ws_[3]);
}

// --------------------------------------------------------------- Gram kernel
// Block: 256 threads (4 waves). Wave w owns output rows [32w, 32w+32).
// LDS tile (dword view): ldsd[f][k*16 + p] holds bf16 pair (site 2p, 2p+1)
// => u16 view: row f, kk = k*32 + s, row stride 104 u16 (208 B, 16B-mult).
// K enumeration kk = k*32 + s is a free permutation of the Gram K-dim.
template <int USE_ATOMIC>
__global__ void __launch_bounds__(256, 2) gram_kernel(
        const float* __restrict__ conv, float* __restrict__ out) {
    __shared__ unsigned int lds[FDIM * DSTRIDE_DW];
    const int tid = threadIdx.x;
    const int lane = tid & 63;
    const int wave = tid >> 6;
    const int p = tid >> 4;                 // site pair 0..15
    const int q = tid & 15;                 // float4 sub-offset 0..15

    f32x4 acc0[8], acc1[8];                 // rows wave*32+[0,16) / +[16,32)
#pragma unroll
    for (int cc = 0; cc < 8; ++cc) { acc0[cc] = (f32x4)0.f; acc1[cc] = (f32x4)0.f; }

    for (int c = 0; c < CHUNKS_PER_BLK; ++c) {
        const float4* src4 = reinterpret_cast<const float4*>(
            conv + (size_t)(blockIdx.x * CHUNKS_PER_BLK + c) * CHUNK_FLOATS);
        const float4* s0 = src4 + (2 * p) * F4_PER_SITE + q;
        const float4* s1 = s0 + F4_PER_SITE;
        // ---- stage: 6 iters x (2 float4 loads -> 4 packed b32 LDS writes)
#pragma unroll
        for (int it = 0; it < 6; ++it) {
            float4 v0 = s0[it * 16];
            float4 v1 = s1[it * 16];
            const int off4 = q + it * 16;
#pragma unroll
            for (int u = 0; u < 4; ++u) {
                const int idx = off4 * 4 + u;       // [0,384): f*3 + k
                const int f = idx / 3;              // magic-mul, amortized x2
                const int k = idx - f * 3;
                const float x0 = (u == 0) ? v0.x : (u == 1) ? v0.y : (u == 2) ? v0.z : v0.w;
                const float x1 = (u == 0) ? v1.x : (u == 1) ? v1.y : (u == 2) ? v1.z : v1.w;
                lds[f * DSTRIDE_DW + k * NPAIR + p] = pack_bf2(x0, x1);
            }
        }
        __syncthreads();
        // ---- compute: 3 K-steps x (10 b128 frag loads + 16 MFMA)
        const unsigned short* ldsu = reinterpret_cast<const unsigned short*>(lds);
        const int colr = lane & 15;
        const int hi8 = (lane >> 4) * 8;
#pragma unroll
        for (int ks = 0; ks < 3; ++ks) {
            const int koff = ks * 32 + hi8;
            // A-fragments: named registers, static indices only (rule #20)
            bf16x8 a0 = *reinterpret_cast<const bf16x8*>(
                &ldsu[(wave * 32 + colr) * (DSTRIDE_DW * 2) + koff]);
            bf16x8 a1 = *reinterpret_cast<const bf16x8*>(
                &ldsu[(wave * 32 + 16 + colr) * (DSTRIDE_DW * 2) + koff]);
#pragma unroll
            for (int cc = 0; cc < 8; ++cc) {
                bf16x8 b = *reinterpret_cast<const bf16x8*>(
                    &ldsu[(cc * 16 + colr) * (DSTRIDE_DW * 2) + koff]);
                acc0[cc] = __builtin_amdgcn_mfma_f32_16x16x32_bf16(a0, b, acc0[cc], 0, 0, 0);
                acc1[cc] = __builtin_amdgcn_mfma_f32_16x16x32_bf16(a1, b, acc1[cc], 0, 0, 0);
            }
        }
        __syncthreads();
    }

    // ---- write out. C/D layout: col = lane&15, row = (lane>>4)*4 + j
    float* my = USE_ATOMIC ? out : out + (size_t)blockIdx.x * GRAM_ELEMS;
    const int colb = lane & 15;
    const int rsub = (lane >> 4) << 2;
#pragma unroll
    for (int cc = 0; cc < 8; ++cc) {
        const int col = cc * 16 + colb;
#pragma unroll
        for (int j = 0; j < 4; ++j) {
            const int r0 = wave * 32 + rsub + j;
            const int r1 = r0 + 16;
            if (USE_ATOMIC) {
                atomicAdd(&my[r0 * FDIM + col], acc0[cc][j]);
                atomicAdd(&my[r1 * FDIM + col], acc1[cc][j]);
            } else {
                my[r0 * FDIM + col] = acc0[cc][j];
                my[r1 * FDIM + col] = acc1[cc][j];
            }
        }
    }
}

// ------------------------------------------------- partial-Gram tree reduce
__global__ void __launch_bounds__(256) gram_reduce(
        const float* __restrict__ partials, float* __restrict__ gram) {
    const int gid = blockIdx.x * 256 + threadIdx.x;
    const int e = gid & (GRAM_ELEMS - 1);
    const int slice = gid >> 14;            // 0..7
    float s = 0.f;
#pragma unroll 8
    for (int b = slice * 64; b < slice * 64 + 64; ++b)
        s += partials[(size_t)b * GRAM_ELEMS + e];
    atomicAdd(&gram[e], s);
}

// ------------------------------------------------------------ finalize
__global__ void __launch_bounds__(256) finalize_kernel(
        const float* __restrict__ gram, const float* __restrict__ mse_slot,
        float* __restrict__ out) {
    __shared__ float rn[FDIM];
    __shared__ float red[4];
    const int tid = threadIdx.x;
    if (tid < FDIM) rn[tid] = rsqrtf(gram[tid * (FDIM + 1)]);
    __syncthreads();
    float s = 0.f;
    for (int i = tid; i < GRAM_ELEMS; i += 256) {
        const int row = i >> 7, col = i & 127;
        const float g = gram[i] * rn[row] * rn[col];
        if (row != col && g > TAU && g <= 1.0f) s += g;
    }
    for (int off = 32; off; off >>= 1) s += __shfl_down(s, off);
    if ((tid & 63) == 0) red[tid >> 6] = s;
    __syncthreads();
    if (tid == 0)
        out[0] = mse_slot[0] * (1.0f / 8192000.0f) +
                 ALPHA * (red[0] + red[1] + red[2] + red[3]);
}

extern "C" void kernel_launch(void* const* d_in, const int* in_sizes, int n_in,
                              void* d_out, int out_size, void* d_ws, size_t ws_size,
                              hipStream_t stream) {
    const float* output = (const float*)d_in[0];
    const float* target = (const float*)d_in[1];
    const float* conv   = (const float*)d_in[2];
    float* out = (float*)d_out;

    float* wsf      = (float*)d_ws;
    float* mse_slot = wsf;                       // 1 float (+pad to 64)
    float* gram     = wsf + 64;                  // 16384 floats
    float* partials = wsf + 64 + GRAM_ELEMS;     // 512 * 16384 floats

    const size_t need_partials =
        (64 + GRAM_ELEMS + (size_t)GRAM_NBLK * GRAM_ELEMS) * sizeof(float);

    // zero mse slot + gram accumulator (atomic targets)
    hipMemsetAsync(d_ws, 0, (64 + GRAM_ELEMS) * sizeof(float), stream);

    mse_kernel<<<2048, 256, 0, stream>>>(output, target, mse_slot);

    if (ws_size >= need_partials) {
        gram_kernel<0><<<GRAM_NBLK, 256, 0, stream>>>(conv, partials);
        gram_reduce<<<512, 256, 0, stream>>>(partials, gram);
    } else {
        gram_kernel<1><<<GRAM_NBLK, 256, 0, stream>>>(conv, gram);
    }

    finalize_kernel<<<1, 256, 0, stream>>>(gram, mse_slot, out);
}

// Round 3
// 93.241 us; speedup vs baseline: 2.9899x; 1.0004x over previous
//
#include <hip/hip_runtime.h>
#include <hip/hip_bf16.h>

// loss = mean((output-target)^2) + ALPHA * sum(masked cosine Gram of
// V[128][196608]), V[f][d] = conv_w[o][i][f][k], d=(site,k), site=(o,i).
//
// Round 3: (a) gram blocks atomicAdd straight into the 64KB gram accumulator
// (no 33.5MB partials round-trip, no reduce dispatch); (b) MSE fused into the
// gram kernel as a leading grid-stride phase. 3 dispatches total.

typedef __attribute__((ext_vector_type(8))) short bf16x8;   // 8 bf16 = 4 VGPR
typedef __attribute__((ext_vector_type(4))) float f32x4;

#define ALPHA 0.0005f
#define TAU 0.2f

#define FDIM 128            // filters (Gram size)
#define KW 3
#define SPS 32              // sites staged per chunk
#define NPAIR 16            // site pairs per chunk
#define F4_PER_SITE 96      // 384 floats per site
#define CHUNK_FLOATS (SPS * FDIM * KW)      // 12288 floats = 48 KB
#define DSTRIDE_DW 52       // LDS row stride in dwords (48 data + 4 pad)
#define GRAM_NBLK 512
#define CHUNKS_PER_BLK 4    // 512 * 4 * 32 = 65536 sites
#define GRAM_ELEMS (FDIM * FDIM)            // 16384
#define MSE_N4 ((8192 * 1000) / 4)          // 2,048,000 float4

// branchless RNE f32->bf16 pair pack (inputs are finite random normals)
__device__ inline unsigned int pack_bf2(float lo, float hi) {
    union { float f; unsigned int u; } a, b;
    a.f = lo; b.f = hi;
    unsigned int al = (a.u + 0x7fffu + ((a.u >> 16) & 1u)) >> 16;
    unsigned int bh = (b.u + 0x7fffu + ((b.u >> 16) & 1u)) & 0xffff0000u;
    return (al & 0xffffu) | bh;
}

// ------------------------------------------------- fused MSE + Gram kernel
// Phase 1: grid-stride MSE over 66 MB, one atomicAdd per block.
// Phase 2 (per block): 4 chunks of 32 sites; stage fp32->bf16 transposed LDS
// tile [128][96+pad]; 3 K-steps x 16 MFMA (16x16x32) per wave; block tile is
// full 128x128; atomicAdd the tile into gram[16384].
// Register-array indices are all compile-time (rule #20).
__global__ void __launch_bounds__(256, 2) fused_kernel(
        const float* __restrict__ o, const float* __restrict__ t,
        const float* __restrict__ conv,
        float* __restrict__ mse_slot, float* __restrict__ gram) {
    __shared__ unsigned int lds[FDIM * DSTRIDE_DW];
    __shared__ float red[4];
    const int tid = threadIdx.x;
    const int lane = tid & 63;
    const int wave = tid >> 6;

    // ---------------- phase 1: MSE partial ----------------
    {
        float s = 0.f;
        for (int i = blockIdx.x * blockDim.x + tid; i < MSE_N4;
             i += GRAM_NBLK * 256) {
            float4 a = reinterpret_cast<const float4*>(o)[i];
            float4 b = reinterpret_cast<const float4*>(t)[i];
            float dx = a.x - b.x, dy = a.y - b.y, dz = a.z - b.z, dw = a.w - b.w;
            s += dx * dx + dy * dy + dz * dz + dw * dw;
        }
        for (int off = 32; off; off >>= 1) s += __shfl_down(s, off);
        if (lane == 0) red[wave] = s;
        __syncthreads();
        if (tid == 0)
            atomicAdd(mse_slot, red[0] + red[1] + red[2] + red[3]);
        __syncthreads();
    }

    // ---------------- phase 2: Gram tile ----------------
    const int p = tid >> 4;                 // site pair 0..15
    const int q = tid & 15;                 // float4 sub-offset 0..15

    f32x4 acc0[8], acc1[8];                 // rows wave*32+[0,16) / +[16,32)
#pragma unroll
    for (int cc = 0; cc < 8; ++cc) { acc0[cc] = (f32x4)0.f; acc1[cc] = (f32x4)0.f; }

    for (int c = 0; c < CHUNKS_PER_BLK; ++c) {
        const float4* src4 = reinterpret_cast<const float4*>(
            conv + (size_t)(blockIdx.x * CHUNKS_PER_BLK + c) * CHUNK_FLOATS);
        const float4* s0 = src4 + (2 * p) * F4_PER_SITE + q;
        const float4* s1 = s0 + F4_PER_SITE;
        // ---- stage: 6 iters x (2 float4 loads -> 4 packed b32 LDS writes)
#pragma unroll
        for (int it = 0; it < 6; ++it) {
            float4 v0 = s0[it * 16];
            float4 v1 = s1[it * 16];
            const int off4 = q + it * 16;
#pragma unroll
            for (int u = 0; u < 4; ++u) {
                const int idx = off4 * 4 + u;       // [0,384): f*3 + k
                const int f = idx / 3;              // magic-mul
                const int k = idx - f * 3;
                const float x0 = (u == 0) ? v0.x : (u == 1) ? v0.y : (u == 2) ? v0.z : v0.w;
                const float x1 = (u == 0) ? v1.x : (u == 1) ? v1.y : (u == 2) ? v1.z : v1.w;
                lds[f * DSTRIDE_DW + k * NPAIR + p] = pack_bf2(x0, x1);
            }
        }
        __syncthreads();
        // ---- compute: 3 K-steps x (10 b128 frag loads + 16 MFMA)
        const unsigned short* ldsu = reinterpret_cast<const unsigned short*>(lds);
        const int colr = lane & 15;
        const int hi8 = (lane >> 4) * 8;
#pragma unroll
        for (int ks = 0; ks < 3; ++ks) {
            const int koff = ks * 32 + hi8;
            // A-fragments: named registers, static indices only (rule #20)
            bf16x8 a0 = *reinterpret_cast<const bf16x8*>(
                &ldsu[(wave * 32 + colr) * (DSTRIDE_DW * 2) + koff]);
            bf16x8 a1 = *reinterpret_cast<const bf16x8*>(
                &ldsu[(wave * 32 + 16 + colr) * (DSTRIDE_DW * 2) + koff]);
#pragma unroll
            for (int cc = 0; cc < 8; ++cc) {
                bf16x8 b = *reinterpret_cast<const bf16x8*>(
                    &ldsu[(cc * 16 + colr) * (DSTRIDE_DW * 2) + koff]);
                acc0[cc] = __builtin_amdgcn_mfma_f32_16x16x32_bf16(a0, b, acc0[cc], 0, 0, 0);
                acc1[cc] = __builtin_amdgcn_mfma_f32_16x16x32_bf16(a1, b, acc1[cc], 0, 0, 0);
            }
        }
        __syncthreads();
    }

    // ---- accumulate tile into gram. C/D: col = lane&15, row = (lane>>4)*4+j
    const int colb = lane & 15;
    const int rsub = (lane >> 4) << 2;
#pragma unroll
    for (int cc = 0; cc < 8; ++cc) {
        const int col = cc * 16 + colb;
#pragma unroll
        for (int j = 0; j < 4; ++j) {
            const int r0 = wave * 32 + rsub + j;
            const int r1 = r0 + 16;
            atomicAdd(&gram[r0 * FDIM + col], acc0[cc][j]);
            atomicAdd(&gram[r1 * FDIM + col], acc1[cc][j]);
        }
    }
}

// ------------------------------------------------------------ finalize
__global__ void __launch_bounds__(256) finalize_kernel(
        const float* __restrict__ gram, const float* __restrict__ mse_slot,
        float* __restrict__ out) {
    __shared__ float rn[FDIM];
    __shared__ float red[4];
    const int tid = threadIdx.x;
    if (tid < FDIM) rn[tid] = rsqrtf(gram[tid * (FDIM + 1)]);
    __syncthreads();
    float s = 0.f;
    for (int i = tid; i < GRAM_ELEMS; i += 256) {
        const int row = i >> 7, col = i & 127;
        const float g = gram[i] * rn[row] * rn[col];
        if (row != col && g > TAU && g <= 1.0f) s += g;
    }
    for (int off = 32; off; off >>= 1) s += __shfl_down(s, off);
    if ((tid & 63) == 0) red[tid >> 6] = s;
    __syncthreads();
    if (tid == 0)
        out[0] = mse_slot[0] * (1.0f / 8192000.0f) +
                 ALPHA * (red[0] + red[1] + red[2] + red[3]);
}

extern "C" void kernel_launch(void* const* d_in, const int* in_sizes, int n_in,
                              void* d_out, int out_size, void* d_ws, size_t ws_size,
                              hipStream_t stream) {
    const float* output = (const float*)d_in[0];
    const float* target = (const float*)d_in[1];
    const float* conv   = (const float*)d_in[2];
    float* out = (float*)d_out;

    float* wsf      = (float*)d_ws;
    float* mse_slot = wsf;                       // 1 float (+pad to 64)
    float* gram     = wsf + 64;                  // 16384 floats

    // zero atomic accumulators (mse slot + gram) every call
    hipMemsetAsync(d_ws, 0, (64 + GRAM_ELEMS) * sizeof(float), stream);

    fused_kernel<<<GRAM_NBLK, 256, 0, stream>>>(output, target, conv,
                                                mse_slot, gram);
    finalize_kernel<<<1, 256, 0, stream>>>(gram, mse_slot, out);
}

// Round 4
// 62.810 us; speedup vs baseline: 4.4385x; 1.4845x over previous
//
#include <hip/hip_runtime.h>
#include <hip/hip_bf16.h>

// loss = mean((output-target)^2) + ALPHA * sum(masked cosine Gram of
// V[128][196608]), V[f][d] = conv_w[o][i][f][k], d=(site,k), site=(o,i).
//
// Round 4: BW-first redesign. Gram staging via global_load_lds DMA into a
// double-buffered raw fp32 LDS buffer with counted vmcnt + raw s_barrier
// (loads stay in flight across barriers). 256 blocks (1/CU), 8 chunks each.
// No atomics, no memsets: per-block partial tiles + reduce + finalize.

typedef __attribute__((ext_vector_type(8))) short bf16x8;   // 8 bf16 = 4 VGPR
typedef __attribute__((ext_vector_type(4))) float f32x4;

#define ALPHA 0.0005f
#define TAU 0.2f

#define FDIM 128            // filters (Gram size)
#define NPAIR 16            // site pairs per chunk
#define CHUNK_FLOATS 12288  // 32 sites * 384 floats = 48 KB
#define DSTRIDE_DW 52       // bf16 tile row stride in dwords (48 data + 4 pad)
#define GRAM_NBLK 256
#define CHUNKS_PER_BLK 8    // 256 * 8 * 32 = 65536 sites
#define GRAM_ELEMS (FDIM * FDIM)            // 16384
#define MSE_N4 2048000      // 8192*1000/4 float4 per array

#define AS1 __attribute__((address_space(1)))
#define AS3 __attribute__((address_space(3)))

__device__ inline void gl_lds16(const float* g, float* l) {
    // 16B per lane, LDS dest = wave-uniform base + lane*16
    __builtin_amdgcn_global_load_lds((AS1 const void*)g, (AS3 void*)l, 16, 0, 0);
}

// branchless RNE f32->bf16 pair pack (inputs are finite random normals)
__device__ inline unsigned int pack_bf2(float lo, float hi) {
    union { float f; unsigned int u; } a, b;
    a.f = lo; b.f = hi;
    unsigned int al = (a.u + 0x7fffu + ((a.u >> 16) & 1u)) >> 16;
    unsigned int bh = (b.u + 0x7fffu + ((b.u >> 16) & 1u)) & 0xffff0000u;
    return (al & 0xffffu) | bh;
}

// ------------------------------------------------- fused MSE + Gram kernel
// 256 blocks x 256 threads, 1 block/CU (122.6 KB LDS). Per chunk:
//   issue 12 gl_lds (chunk c+1 -> raw[cur^1])     [48 KB DMA, stays in flight]
//   vmcnt(12) ; lgkmcnt(0) ; s_barrier            [raw[cur] ready, tile free]
//   convert raw[cur] -> bf16 transposed tile      [12 b128 reads, 24 b32 writes]
//   lgkmcnt(0) ; s_barrier                        [tile ready]
//   3 K-steps x (10 b128 frag reads + 16 MFMA)    [per wave, rows 32w..32w+31]
__global__ void __launch_bounds__(256) fused_kernel(
        const float* __restrict__ o, const float* __restrict__ t,
        const float* __restrict__ conv,
        float* __restrict__ mse_part, float* __restrict__ partials) {
    __shared__ float raw[2][CHUNK_FLOATS];              // 96 KB
    __shared__ unsigned int tile[FDIM * DSTRIDE_DW];    // 26.6 KB
    __shared__ float red[4];
    const int tid = threadIdx.x;
    const int lane = tid & 63;
    const int wave = tid >> 6;
    const size_t blk_chunk0 = (size_t)blockIdx.x * CHUNKS_PER_BLK;

    // -------- prologue: issue chunk-0 DMA (overlaps MSE phase)
    {
        const float* g0 = conv + blk_chunk0 * CHUNK_FLOATS;
#pragma unroll
        for (int it = 0; it < 12; ++it)
            gl_lds16(g0 + (it * 256 + tid) * 4,
                     &raw[0][(it * 256 + wave * 64) * 4]);
    }

    // -------- phase 1: MSE partial (65536 threads x 31.25 f4-pairs)
    {
        const int gid = blockIdx.x * 256 + tid;
        const float4* o4 = reinterpret_cast<const float4*>(o);
        const float4* t4 = reinterpret_cast<const float4*>(t);
        float s = 0.f;
        int i = gid;
#pragma unroll 4
        for (int k = 0; k < 31; ++k) {
            float4 a = o4[i], b = t4[i];
            float dx = a.x - b.x, dy = a.y - b.y, dz = a.z - b.z, dw = a.w - b.w;
            s += dx * dx + dy * dy + dz * dz + dw * dw;
            i += 65536;
        }
        if (gid < MSE_N4 - 31 * 65536) {            // 16384 tail threads
            float4 a = o4[i], b = t4[i];
            float dx = a.x - b.x, dy = a.y - b.y, dz = a.z - b.z, dw = a.w - b.w;
            s += dx * dx + dy * dy + dz * dz + dw * dw;
        }
        for (int off = 32; off; off >>= 1) s += __shfl_down(s, off);
        if (lane == 0) red[wave] = s;
        __syncthreads();
        if (tid == 0) mse_part[blockIdx.x] = red[0] + red[1] + red[2] + red[3];
    }

    // -------- phase 2: Gram tile, DMA-pipelined chunks
    f32x4 acc0[8], acc1[8];                 // rows wave*32+[0,16) / +[16,32)
#pragma unroll
    for (int cc = 0; cc < 8; ++cc) { acc0[cc] = (f32x4)0.f; acc1[cc] = (f32x4)0.f; }

    const int p = tid >> 4;                 // site pair 0..15
    const int q = tid & 15;                 // float4 sub-offset 0..15
    const int colr = lane & 15;
    const int hi8 = (lane >> 4) * 8;
    const unsigned short* tileu = reinterpret_cast<const unsigned short*>(tile);

    for (int c = 0; c < CHUNKS_PER_BLK; ++c) {
        const int cur = c & 1;
        // issue next chunk's DMA, then wait for current chunk (counted vmcnt)
        if (c + 1 < CHUNKS_PER_BLK) {
            const float* gn = conv + (blk_chunk0 + c + 1) * CHUNK_FLOATS;
            float* rn_ = &raw[cur ^ 1][0];
#pragma unroll
            for (int it = 0; it < 12; ++it)
                gl_lds16(gn + (it * 256 + tid) * 4, rn_ + (it * 256 + wave * 64) * 4);
            asm volatile("s_waitcnt vmcnt(12)" ::: "memory");
        } else {
            asm volatile("s_waitcnt vmcnt(0)" ::: "memory");
        }
        asm volatile("s_waitcnt lgkmcnt(0)" ::: "memory");
        __builtin_amdgcn_s_barrier();       // raw[cur] ready AND tile(c-1) consumed
        asm volatile("" ::: "memory");

        // ---- convert raw[cur] -> transposed bf16 tile (pair-packed b32)
        const float4* r0 = reinterpret_cast<const float4*>(&raw[cur][0])
                           + (2 * p) * 96 + q;
        const float4* r1 = r0 + 96;
#pragma unroll
        for (int it = 0; it < 6; ++it) {
            float4 v0 = r0[it * 16];
            float4 v1 = r1[it * 16];
            const int off4 = q + it * 16;
#pragma unroll
            for (int u = 0; u < 4; ++u) {
                const int idx = off4 * 4 + u;       // [0,384): f*3 + k
                const int f = idx / 3;              // magic-mul
                const int k = idx - f * 3;
                const float x0 = (u == 0) ? v0.x : (u == 1) ? v0.y : (u == 2) ? v0.z : v0.w;
                const float x1 = (u == 0) ? v1.x : (u == 1) ? v1.y : (u == 2) ? v1.z : v1.w;
                tile[f * DSTRIDE_DW + k * NPAIR + p] = pack_bf2(x0, x1);
            }
        }
        asm volatile("s_waitcnt lgkmcnt(0)" ::: "memory");
        __builtin_amdgcn_s_barrier();       // tile ready for all waves
        asm volatile("" ::: "memory");

        // ---- MFMA: 3 K-steps x (2 A-frags + 8 B-frags, 16 MFMA)
#pragma unroll
        for (int ks = 0; ks < 3; ++ks) {
            const int koff = ks * 32 + hi8;
            bf16x8 a0 = *reinterpret_cast<const bf16x8*>(
                &tileu[(wave * 32 + colr) * (DSTRIDE_DW * 2) + koff]);
            bf16x8 a1 = *reinterpret_cast<const bf16x8*>(
                &tileu[(wave * 32 + 16 + colr) * (DSTRIDE_DW * 2) + koff]);
#pragma unroll
            for (int cc = 0; cc < 8; ++cc) {
                bf16x8 b = *reinterpret_cast<const bf16x8*>(
                    &tileu[(cc * 16 + colr) * (DSTRIDE_DW * 2) + koff]);
                acc0[cc] = __builtin_amdgcn_mfma_f32_16x16x32_bf16(a0, b, acc0[cc], 0, 0, 0);
                acc1[cc] = __builtin_amdgcn_mfma_f32_16x16x32_bf16(a1, b, acc1[cc], 0, 0, 0);
            }
        }
    }

    // ---- store per-block partial tile (streaming, no atomics)
    float* myp = partials + (size_t)blockIdx.x * GRAM_ELEMS;
    const int rsub = (lane >> 4) << 2;
#pragma unroll
    for (int cc = 0; cc < 8; ++cc) {
        const int col = cc * 16 + colr;
#pragma unroll
        for (int j = 0; j < 4; ++j) {
            const int r0w = wave * 32 + rsub + j;
            myp[r0w * FDIM + col] = acc0[cc][j];
            myp[(r0w + 16) * FDIM + col] = acc1[cc][j];
        }
    }
}

// ------------------------------------------------- partial-Gram tree reduce
// 256 blocks x 256 thr: entry e = blk*64 + (tid&63); 4 slices of 64 partials
// each, combined through padded LDS. Coalesced 256B reads per (b, e-group).
__global__ void __launch_bounds__(256) reduce_kernel(
        const float* __restrict__ partials, float* __restrict__ gram) {
    __shared__ float acc_s[64][5];
    const int tid = threadIdx.x;
    const int el = tid & 63;
    const int sl = tid >> 6;                // 0..3
    const int e = blockIdx.x * 64 + el;
    float s = 0.f;
#pragma unroll 8
    for (int b = sl * 64; b < sl * 64 + 64; ++b)
        s += partials[(size_t)b * GRAM_ELEMS + e];
    acc_s[el][sl] = s;
    __syncthreads();
    if (tid < 64)
        gram[blockIdx.x * 64 + tid] =
            acc_s[tid][0] + acc_s[tid][1] + acc_s[tid][2] + acc_s[tid][3];
}

// ------------------------------------------------------------ finalize
__global__ void __launch_bounds__(256) finalize_kernel(
        const float* __restrict__ gram, const float* __restrict__ mse_part,
        float* __restrict__ out) {
    __shared__ float rn[FDIM];
    __shared__ float red[4];
    __shared__ float redm[4];
    const int tid = threadIdx.x;
    if (tid < FDIM) rn[tid] = rsqrtf(gram[tid * (FDIM + 1)]);
    __syncthreads();
    float s = 0.f;
    for (int i = tid; i < GRAM_ELEMS; i += 256) {
        const int row = i >> 7, col = i & 127;
        const float g = gram[i] * rn[row] * rn[col];
        if (row != col && g > TAU && g <= 1.0f) s += g;
    }
    float m = mse_part[tid];                // exactly 256 entries
    for (int off = 32; off; off >>= 1) {
        s += __shfl_down(s, off);
        m += __shfl_down(m, off);
    }
    if ((tid & 63) == 0) { red[tid >> 6] = s; redm[tid >> 6] = m; }
    __syncthreads();
    if (tid == 0)
        out[0] = (redm[0] + redm[1] + redm[2] + redm[3]) * (1.0f / 8192000.0f) +
                 ALPHA * (red[0] + red[1] + red[2] + red[3]);
}

extern "C" void kernel_launch(void* const* d_in, const int* in_sizes, int n_in,
                              void* d_out, int out_size, void* d_ws, size_t ws_size,
                              hipStream_t stream) {
    const float* output = (const float*)d_in[0];
    const float* target = (const float*)d_in[1];
    const float* conv   = (const float*)d_in[2];
    float* out = (float*)d_out;

    float* wsf      = (float*)d_ws;
    float* mse_part = wsf;                           // 256 floats
    float* gram     = wsf + 256;                     // 16384 floats
    float* partials = wsf + 256 + GRAM_ELEMS;        // 256*16384 floats (16.8MB)
    // total need ~16.84 MB; ws >= 33.6 MB proven by round-2 partials path.
    (void)ws_size;

    // every buffer is fully written before being read -> no memsets needed
    fused_kernel<<<GRAM_NBLK, 256, 0, stream>>>(output, target, conv,
                                                mse_part, partials);
    reduce_kernel<<<GRAM_ELEMS / 64, 256, 0, stream>>>(partials, gram);
    finalize_kernel<<<1, 256, 0, stream>>>(gram, mse_part, out);
}

// Round 5
// 62.029 us; speedup vs baseline: 4.4944x; 1.0126x over previous
//
#include <hip/hip_runtime.h>
#include <hip/hip_bf16.h>

// loss = mean((output-target)^2) + ALPHA * sum(masked cosine Gram of
// V[128][196608]), V[f][d] = conv_w[o][i][f][k], d=(site,k), site=(o,i).
//
// Round 5: TLP-first split. mse (2048 blk) / gram (512 blk, 2/CU, reg-staged
// T14 prefetch, double-buffered tile, 1 raw-barrier per chunk, no vmcnt
// drains) / reduce / finalize. Phases isolated for per-kernel counters.

typedef __attribute__((ext_vector_type(8))) short bf16x8;   // 8 bf16 = 4 VGPR
typedef __attribute__((ext_vector_type(4))) float f32x4;

#define ALPHA 0.0005f
#define TAU 0.2f

#define FDIM 128
#define TSTRIDE_DW 52       // tile row stride in dwords (48 data + 4 pad)
#define GRAM_NBLK 512
#define CHUNK_F4 3072       // 32 sites * 96 float4
#define GRAM_ELEMS (FDIM * FDIM)
#define MSE_N4 2048000      // 8192*1000/4
#define MSE_NBLK 2048

// branchless RNE f32->bf16 pair pack
__device__ __forceinline__ unsigned int pack_bf2(float lo, float hi) {
    union { float f; unsigned int u; } a, b;
    a.f = lo; b.f = hi;
    unsigned int al = (a.u + 0x7fffu + ((a.u >> 16) & 1u)) >> 16;
    unsigned int bh = (b.u + 0x7fffu + ((b.u >> 16) & 1u)) & 0xffff0000u;
    return (al & 0xffffu) | bh;
}

// ---------------------------------------------------------------- MSE kernel
__global__ void __launch_bounds__(256) mse_kernel(
        const float* __restrict__ o, const float* __restrict__ t,
        float* __restrict__ mse_part) {
    __shared__ float red[4];
    const int tid = threadIdx.x;
    const float4* o4 = reinterpret_cast<const float4*>(o);
    const float4* t4 = reinterpret_cast<const float4*>(t);
    float s = 0.f;
    for (int i = blockIdx.x * 256 + tid; i < MSE_N4; i += MSE_NBLK * 256) {
        float4 a = o4[i], b = t4[i];
        float dx = a.x - b.x, dy = a.y - b.y, dz = a.z - b.z, dw = a.w - b.w;
        s += dx * dx + dy * dy + dz * dz + dw * dw;
    }
    for (int off = 32; off; off >>= 1) s += __shfl_down(s, off);
    if ((tid & 63) == 0) red[tid >> 6] = s;
    __syncthreads();
    if (tid == 0) mse_part[blockIdx.x] = red[0] + red[1] + red[2] + red[3];
}

// --------------------------------------------------------------- Gram pieces
__device__ __forceinline__ void loadc(const f32x4* __restrict__ src4,
                                      size_t base4, f32x4 (&R)[12]) {
#pragma unroll
    for (int it = 0; it < 6; ++it) {
        R[2 * it]     = src4[base4 + 16 * it];        // site 2p
        R[2 * it + 1] = src4[base4 + 96 + 16 * it];   // site 2p+1
    }
}

__device__ __forceinline__ void convertc(const f32x4 (&R)[12],
                                         unsigned int* __restrict__ tb,
                                         int p, int q) {
#pragma unroll
    for (int it = 0; it < 6; ++it)
#pragma unroll
        for (int u = 0; u < 4; ++u) {
            const int idx = (q + 16 * it) * 4 + u;    // [0,384): f*3 + k
            const int f = idx / 3;                    // magic-mul div
            const int k = idx - 3 * f;
            tb[f * TSTRIDE_DW + k * 16 + p] = pack_bf2(R[2 * it][u], R[2 * it + 1][u]);
        }
}

__device__ __forceinline__ void barrier_tile() {
    // drain own ds_writes, then raw barrier; no vmcnt drain (prefetch stays
    // in flight). sched_barrier pins ds ops on the correct side (rule 18).
    asm volatile("s_waitcnt lgkmcnt(0)" ::: "memory");
    __builtin_amdgcn_sched_barrier(0);
    __builtin_amdgcn_s_barrier();
    __builtin_amdgcn_sched_barrier(0);
}

__device__ __forceinline__ void mfmaph(const unsigned short* __restrict__ tu,
                                       int wave, int colr, int hi8,
                                       f32x4 (&acc0)[8], f32x4 (&acc1)[8]) {
#pragma unroll
    for (int ks = 0; ks < 3; ++ks) {
        const int koff = ks * 32 + hi8;
        bf16x8 a0 = *reinterpret_cast<const bf16x8*>(
            &tu[(wave * 32 + colr) * (TSTRIDE_DW * 2) + koff]);
        bf16x8 a1 = *reinterpret_cast<const bf16x8*>(
            &tu[(wave * 32 + 16 + colr) * (TSTRIDE_DW * 2) + koff]);
#pragma unroll
        for (int cc = 0; cc < 8; ++cc) {
            bf16x8 b = *reinterpret_cast<const bf16x8*>(
                &tu[(cc * 16 + colr) * (TSTRIDE_DW * 2) + koff]);
            acc0[cc] = __builtin_amdgcn_mfma_f32_16x16x32_bf16(a0, b, acc0[cc], 0, 0, 0);
            acc1[cc] = __builtin_amdgcn_mfma_f32_16x16x32_bf16(a1, b, acc1[cc], 0, 0, 0);
        }
    }
}

// 512 blocks x 256 thr, 2 blocks/CU. 4 chunks of 32 sites; reg-staged
// prefetch (RA/RB ping-pong), double-buffered bf16 tile, 1 barrier/chunk.
template <int ATOMIC>
__global__ void __launch_bounds__(256, 2) gram_kernel(
        const float* __restrict__ conv, float* __restrict__ out) {
    __shared__ unsigned int tile[2][FDIM * TSTRIDE_DW];   // 2 x 26.6 KB
    const int tid = threadIdx.x;
    const int lane = tid & 63;
    const int wave = tid >> 6;
    const int p = tid >> 4;                 // site pair 0..15
    const int q = tid & 15;                 // float4 sub-offset 0..15
    const int colr = lane & 15;
    const int hi8 = (lane >> 4) * 8;
    const unsigned short* t0u = reinterpret_cast<const unsigned short*>(tile[0]);
    const unsigned short* t1u = reinterpret_cast<const unsigned short*>(tile[1]);

    f32x4 acc0[8], acc1[8];
#pragma unroll
    for (int cc = 0; cc < 8; ++cc) { acc0[cc] = (f32x4)0.f; acc1[cc] = (f32x4)0.f; }

    const f32x4* src4 = reinterpret_cast<const f32x4*>(conv);
    const size_t cb = (size_t)blockIdx.x * (4 * CHUNK_F4) + (2 * p) * 96 + q;

    f32x4 RA[12], RB[12];
    loadc(src4, cb + 0 * CHUNK_F4, RA);               // chunk 0

    // chunk 0
    loadc(src4, cb + 1 * CHUNK_F4, RB);               // prefetch chunk 1
    convertc(RA, tile[0], p, q);
    barrier_tile();
    mfmaph(t0u, wave, colr, hi8, acc0, acc1);
    // chunk 1
    loadc(src4, cb + 2 * CHUNK_F4, RA);               // prefetch chunk 2
    convertc(RB, tile[1], p, q);
    barrier_tile();
    mfmaph(t1u, wave, colr, hi8, acc0, acc1);
    // chunk 2
    loadc(src4, cb + 3 * CHUNK_F4, RB);               // prefetch chunk 3
    convertc(RA, tile[0], p, q);
    barrier_tile();
    mfmaph(t0u, wave, colr, hi8, acc0, acc1);
    // chunk 3
    convertc(RB, tile[1], p, q);
    barrier_tile();
    mfmaph(t1u, wave, colr, hi8, acc0, acc1);

    // write per-block partial tile (or atomic fallback)
    float* my = ATOMIC ? out : out + (size_t)blockIdx.x * GRAM_ELEMS;
    const int rsub = (lane >> 4) << 2;
#pragma unroll
    for (int cc = 0; cc < 8; ++cc) {
        const int col = cc * 16 + colr;
#pragma unroll
        for (int j = 0; j < 4; ++j) {
            const int r0 = wave * 32 + rsub + j;
            if (ATOMIC) {
                atomicAdd(&my[r0 * FDIM + col], acc0[cc][j]);
                atomicAdd(&my[(r0 + 16) * FDIM + col], acc1[cc][j]);
            } else {
                my[r0 * FDIM + col] = acc0[cc][j];
                my[(r0 + 16) * FDIM + col] = acc1[cc][j];
            }
        }
    }
}

// ------------------------------------------------- partial-Gram tree reduce
// 256 blocks x 256 thr: entry e = blk*64 + (tid&63); 4 slices of 128
// partials; coalesced 256B reads per (b, e-group); unroll 16 for MLP.
__global__ void __launch_bounds__(256) reduce_kernel(
        const float* __restrict__ partials, float* __restrict__ gram) {
    __shared__ float acc_s[64][5];
    const int tid = threadIdx.x;
    const int el = tid & 63;
    const int sl = tid >> 6;                // 0..3
    const int e = blockIdx.x * 64 + el;
    float s = 0.f;
#pragma unroll 16
    for (int b = sl * 128; b < sl * 128 + 128; ++b)
        s += partials[(size_t)b * GRAM_ELEMS + e];
    acc_s[el][sl] = s;
    __syncthreads();
    if (tid < 64)
        gram[blockIdx.x * 64 + tid] =
            acc_s[tid][0] + acc_s[tid][1] + acc_s[tid][2] + acc_s[tid][3];
}

// ------------------------------------------------------------ finalize
__global__ void __launch_bounds__(256) finalize_kernel(
        const float* __restrict__ gram, const float* __restrict__ mse_part,
        float* __restrict__ out) {
    __shared__ float rn[FDIM];
    __shared__ float red[4];
    __shared__ float redm[4];
    const int tid = threadIdx.x;
    if (tid < FDIM) rn[tid] = rsqrtf(gram[tid * (FDIM + 1)]);
    __syncthreads();
    float s = 0.f;
    for (int i = tid; i < GRAM_ELEMS; i += 256) {
        const int row = i >> 7, col = i & 127;
        const float g = gram[i] * rn[row] * rn[col];
        if (row != col && g > TAU && g <= 1.0f) s += g;
    }
    float m = 0.f;
#pragma unroll 8
    for (int j = 0; j < 8; ++j) m += mse_part[tid * 8 + j];   // 2048 entries
    for (int off = 32; off; off >>= 1) {
        s += __shfl_down(s, off);
        m += __shfl_down(m, off);
    }
    if ((tid & 63) == 0) { red[tid >> 6] = s; redm[tid >> 6] = m; }
    __syncthreads();
    if (tid == 0)
        out[0] = (redm[0] + redm[1] + redm[2] + redm[3]) * (1.0f / 8192000.0f) +
                 ALPHA * (red[0] + red[1] + red[2] + red[3]);
}

extern "C" void kernel_launch(void* const* d_in, const int* in_sizes, int n_in,
                              void* d_out, int out_size, void* d_ws, size_t ws_size,
                              hipStream_t stream) {
    const float* output = (const float*)d_in[0];
    const float* target = (const float*)d_in[1];
    const float* conv   = (const float*)d_in[2];
    float* out = (float*)d_out;

    float* wsf      = (float*)d_ws;
    float* mse_part = wsf;                           // 2048 floats
    float* gram     = wsf + MSE_NBLK;                // 16384 floats
    float* partials = wsf + MSE_NBLK + GRAM_ELEMS;   // 512*16384 floats

    const size_t need =
        (MSE_NBLK + GRAM_ELEMS + (size_t)GRAM_NBLK * GRAM_ELEMS) * sizeof(float);

    if (ws_size >= need) {
        gram_kernel<0><<<GRAM_NBLK, 256, 0, stream>>>(conv, partials);
        mse_kernel<<<MSE_NBLK, 256, 0, stream>>>(output, target, mse_part);
        reduce_kernel<<<GRAM_ELEMS / 64, 256, 0, stream>>>(partials, gram);
    } else {
        hipMemsetAsync(gram, 0, GRAM_ELEMS * sizeof(float), stream);
        gram_kernel<1><<<GRAM_NBLK, 256, 0, stream>>>(conv, gram);
        mse_kernel<<<MSE_NBLK, 256, 0, stream>>>(output, target, mse_part);
    }
    finalize_kernel<<<1, 256, 0, stream>>>(gram, mse_part, out);
}